// Round 3
// baseline (440.867 us; speedup 1.0000x reference)
//
#include <hip/hip_runtime.h>

using u16 = unsigned short;
using u64 = unsigned long long;
typedef short s16x8 __attribute__((ext_vector_type(8)));
typedef _Float16 f16x8 __attribute__((ext_vector_type(8)));
typedef unsigned short u16x4 __attribute__((ext_vector_type(4)));
typedef float f32x4 __attribute__((ext_vector_type(4)));

// Problem constants (fixed by reference)
constexpr int BATCH = 64, SEQ = 1024, FEAT = 512, NBINS = 32;
constexpr int N = BATCH * SEQ;              // 65536 samples
constexpr int TAB = 131072;                 // hash table slots (2N), pow2
constexpr unsigned TABMASK = TAB - 1;
constexpr u64 EMPTY = ~0ull;                // combined <= 2^32-1, safe sentinel
constexpr double FXSCALE = 67108864.0;      // 2^26 fixed-point for stat atomics
constexpr int NSHADOW = 64;                 // shadow accumulators (R7)
constexpr int NBLK_A = 1024;                // colstats grid

// NOTE (R4): JAX reference under default config runs int64 as int32;
// left_shift(env, 32) on int32 is 0 in XLA -> combined id is the 32-bit key
// ONLY (env dropped). Verified R5/R6/R7 + MFMA rounds: absmax 0.0.

// Workspace layout (bytes)
constexpr size_t OFF_KEYS = 0;              // u64[TAB]       1048576 (memset 0xFF)
constexpr size_t OFF_HEAD = 1048576;        // i32[TAB]       524288  (memset 0xFF -> -1)
constexpr size_t OFF_CNT = 1572864;         // u32[TAB]       524288  (memset 0x00)
constexpr size_t OFF_SHAD = 2097152;        // u64[64][1024]  524288  (memset 0x00)
constexpr size_t OFF_FLAG = 2621440;        // u32 last-block flag, 64 B (memset 0x00)
constexpr size_t OFF_QD = 2621504;          // f64[16384]     131072  (Q = P/sigma, f64)
constexpr size_t OFF_CD = 2752576;          // f64[32]        256
constexpr size_t OFF_CF = 2818304;          // f32[32]        128
constexpr size_t OFF_SLOT = 2818432;        // i32[N]         262144
constexpr size_t OFF_NEXT = 3080576;        // i32[N]         262144
constexpr size_t OFF_QFRAG = 3342720;       // u16[16384]     32768 f16 B-frags
// qfrag layout: [ch(4)][ks(4)][bt(2)][lane(64)][j(8)] f16 bits
// element = B[k][bin], k = ch*128+ks*32+(lane>>4)*8+j, bin = bt*16+(lane&15)

__device__ inline u16 f2h(float f) {  // f32 -> f16 RNE (hardware cvt)
  _Float16 h = (_Float16)f;
  return __builtin_bit_cast(u16, h);
}

// ---------------- Kernel A: per-column sum / sumsq (f64, fixed-point atomics
// into 64 shadow arrays) + FUSED finalize in the last block (saves a
// single-block dispatch). Shadow writes are device-scope atomics; the
// last block re-reads them after a __threadfence() acquire-equivalent.
__global__ __launch_bounds__(256, 4) void colstats_kernel(
    const float4* __restrict__ xv,  // f32 features, 8388608 float4s
    const float* __restrict__ P,    // f32 [512][32]
    u64* __restrict__ shad, unsigned* __restrict__ flag,
    double* __restrict__ Qd, u16* __restrict__ qfrag,
    double* __restrict__ cd, float* __restrict__ cf) {
  __shared__ double red[256 * 8];  // 16 KB; reused as finalize scratch
  __shared__ bool isLast;
  const int t = threadIdx.x;
  const int L = blockIdx.x * 256 + t;
  double s0 = 0, s1 = 0, s2 = 0, s3 = 0, q0 = 0, q1 = 0, q2 = 0, q3 = 0;
  for (int mm = 0; mm < 32; mm += 8) {
    float4 v[8];
#pragma unroll
    for (int u = 0; u < 8; u++) v[u] = xv[L + (mm + u) * 262144];
#pragma unroll
    for (int u = 0; u < 8; u++) {
      double a = (double)v[u].x, b = (double)v[u].y;
      double c = (double)v[u].z, d = (double)v[u].w;
      s0 += a; s1 += b; s2 += c; s3 += d;
      q0 += a * a; q1 += b * b; q2 += c * c; q3 += d * d;
    }
  }
  red[t * 8 + 0] = s0; red[t * 8 + 1] = s1; red[t * 8 + 2] = s2; red[t * 8 + 3] = s3;
  red[t * 8 + 4] = q0; red[t * 8 + 5] = q1; red[t * 8 + 6] = q2; red[t * 8 + 7] = q3;
  __syncthreads();
  if (t < 128) {
    double v[8];
#pragma unroll
    for (int u = 0; u < 8; u++) v[u] = red[t * 8 + u] + red[(t + 128) * 8 + u];
    const int c0 = 4 * t;
    u64* sh = shad + (size_t)(blockIdx.x & (NSHADOW - 1)) * 1024;
#pragma unroll
    for (int u = 0; u < 4; u++) {
      long long a = (long long)llrint(v[u] * FXSCALE);
      long long b = (long long)llrint(v[4 + u] * FXSCALE);
      atomicAdd(&sh[c0 + u], (u64)a);
      atomicAdd(&sh[512 + c0 + u], (u64)b);
    }
  }
  // ---- last-block-done handoff
  __threadfence();   // release: shadow atomics visible device-wide
  __syncthreads();
  if (t == 0) isLast = (atomicAdd(flag, 1u) == (unsigned)(NBLK_A - 1));
  __syncthreads();
  if (!isLast) return;
  __threadfence();   // acquire side: order flag read before shadow re-reads

  // ---- finalize (256 threads handle 512 features in 2 halves)
  double* meanArr = red;         // [512]
  double* invArr = red + 512;    // [512]
  double* part = red + 1024;     // [16][32]
#pragma unroll
  for (int half = 0; half < 2; half++) {
    const int f = t + half * 256;  // feature index
    long long isum = 0, isumsq = 0;
    for (int sh = 0; sh < NSHADOW; sh++) {  // exact int adds, order-free
      isum += (long long)__hip_atomic_load(&shad[sh * 1024 + f],
                                           __ATOMIC_RELAXED, __HIP_MEMORY_SCOPE_AGENT);
      isumsq += (long long)__hip_atomic_load(&shad[sh * 1024 + 512 + f],
                                             __ATOMIC_RELAXED, __HIP_MEMORY_SCOPE_AGENT);
    }
    const double Nd = (double)N;
    const double tot = 1e-4 + Nd;
    double s = (double)isum * (1.0 / FXSCALE);
    double ss = (double)isumsq * (1.0 / FXSCALE);
    double bm = s / Nd;
    double bv = (ss - s * s / Nd) / (Nd - 1.0);  // unbiased var
    double mean = bm * Nd / tot;
    double M2 = 1e-4 + bv * Nd + bm * bm * 1e-4 * Nd / tot;
    double var = M2 / tot;
    double inv = 1.0 / sqrt(var + 1e-8);
    meanArr[f] = mean;
    invArr[f] = inv;
    // scatter f16 B-fragments (MFMA B lane order) + f64 Q for recheck
    const int ch = f >> 7, ks = (f >> 5) & 3, kg = (f >> 3) & 3, jlo = f & 7;
#pragma unroll
    for (int j = 0; j < NBINS; j++) {
      double qd = (double)P[f * NBINS + j] * inv;
      Qd[f * NBINS + j] = qd;
      const int lane = (j & 15) | (kg << 4);
      const int bt = j >> 4;
      qfrag[(size_t)((((ch * 4 + ks) * 2 + bt) * 64 + lane) * 8 + jlo)] =
          f2h((float)qd);
    }
  }
  __syncthreads();
#pragma unroll
  for (int half = 0; half < 2; half++) {
    const int tt = t + half * 256;
    const int j = tt & 31, g = tt >> 5;  // 16 groups x 32 feats
    double p = 0.0;
    for (int f = g * 32; f < g * 32 + 32; f++)
      p += meanArr[f] * ((double)P[f * NBINS + j] * invArr[f]);
    part[g * NBINS + j] = p;
  }
  __syncthreads();
  if (t < NBINS) {
    double c = 0.0;
    for (int g = 0; g < 16; g++) c += part[g * NBINS + t];  // fixed order
    cd[t] = c;
    cf[t] = (float)c;
  }
}

// ---------------- Kernel C: single-term f16 MFMA projection + hash insert.
// S = f16(x)*f16(q) accumulated in f32 MFMA. Margin error: sigma ~ 2.5e-4
// over K=512 (f16 u=2^-11), expected max over 2M bins ~ 1.4e-3. TAU = 4e-3
// (~16 sigma): any sign-ambiguous bin is re-decided by the wave-cooperative
// f64 dot (validated path, unchanged). Recheck rate ~1.6 bins/wave.
constexpr float TAU = 4e-3f;
__global__ __launch_bounds__(256, 3) void project_kernel(
    const float4* __restrict__ xv, const float* __restrict__ feat,
    const u16* __restrict__ qfrag, const float* __restrict__ cf,
    const double* __restrict__ Qd, const double* __restrict__ cd,
    u64* __restrict__ keys_tab, int* __restrict__ head,
    unsigned* __restrict__ cnt, int* __restrict__ slot, int* __restrict__ nxt) {
  // A-frag LDS: [tile(w)*4+ks (16)][perm-lane (64)][j (8)] f16, 16 KB
  __shared__ __align__(16) u16 xh_lds[8192];
  __shared__ unsigned keyParts[64];
  const int t = threadIdx.x;
  const int rowBase = blockIdx.x * 64;
  const int lane = t & 63;
  const int w = t >> 6;  // wave id: owns rows rowBase + w*16 .. +16, all 32 bins
  if (t < 64) keyParts[t] = 0u;

  f32x4 acc0 = {0.f, 0.f, 0.f, 0.f};  // bins 0..15
  f32x4 acc1 = {0.f, 0.f, 0.f, 0.f};  // bins 16..31
  for (int ch = 0; ch < 4; ch++) {  // K chunks of 128
    __syncthreads();                // protects keyParts init / LDS reuse
    // B-fragments for this chunk -> 32 VGPRs (coalesced, L2-hot)
    s16x8 B[4][2];
#pragma unroll
    for (int ks = 0; ks < 4; ks++)
#pragma unroll
      for (int bt = 0; bt < 2; bt++)
        B[ks][bt] = *(const s16x8*)&qfrag[(size_t)((((ch * 4 + ks) * 2 + bt) * 64 + lane) * 8)];
    // stage X chunk: 64 rows x 32 float4 -> f16 in frag order (XOR swizzle)
#pragma unroll
    for (int kk = 0; kk < 8; kk++) {
      const int vi = t + kk * 256;
      const int r = vi >> 5, f4 = vi & 31;
      float4 v = xv[(size_t)(rowBase + r) * 128 + ch * 32 + f4];
      const int ks = f4 >> 3, kg = (f4 & 7) >> 1, j0 = (f4 & 1) * 4;
      const int lane_ = (r & 15) | (kg << 4);
      const int blk = ((r >> 4) * 4 + ks) * 64 + (lane_ ^ (((lane_ >> 4) & 3) << 1));
      u16x4 hv;
      hv[0] = f2h(v.x); hv[1] = f2h(v.y); hv[2] = f2h(v.z); hv[3] = f2h(v.w);
      *(u16x4*)&xh_lds[blk * 8 + j0] = hv;
    }
    __syncthreads();
    // MFMA: 4 k-steps x 2 bin-tiles
#pragma unroll
    for (int ks = 0; ks < 4; ks++) {
      const int rblk = (w * 4 + ks) * 64 + (lane ^ (((lane >> 4) & 3) << 1));
      f16x8 a = __builtin_bit_cast(f16x8, *(const s16x8*)&xh_lds[rblk * 8]);
      acc0 = __builtin_amdgcn_mfma_f32_16x16x32_f16(
          a, __builtin_bit_cast(f16x8, B[ks][0]), acc0, 0, 0, 0);
      acc1 = __builtin_amdgcn_mfma_f32_16x16x32_f16(
          a, __builtin_bit_cast(f16x8, B[ks][1]), acc1, 0, 0, 0);
    }
  }
  // C/D layout (verified): col = lane&15, row = (lane>>4)*4 + reg
  const int colbin = lane & 15;
  float m0[4], m1[4];
  bool b0[4], b1[4];
  const float c0v = cf[colbin], c1v = cf[16 + colbin];
#pragma unroll
  for (int rg = 0; rg < 4; rg++) {
    m0[rg] = acc0[rg] - c0v;
    m1[rg] = acc1[rg] - c1v;
    b0[rg] = m0[rg] > 0.0f;
    b1[rg] = m1[rg] > 0.0f;
  }
  // wave-cooperative f64 recheck of borderline bins (uniform control flow)
#pragma unroll
  for (int bt = 0; bt < 2; bt++)
#pragma unroll
    for (int rg = 0; rg < 4; rg++) {
      const float mv = (bt == 0) ? m0[rg] : m1[rg];
      u64 mask = __ballot(fabsf(mv) < TAU);
      while (mask) {
        const int L = (int)__builtin_ctzll(mask);
        mask &= mask - 1;
        const int jj = bt * 16 + (L & 15);
        const int row = rowBase + w * 16 + (L >> 4) * 4 + rg;
        const float* xr = feat + (size_t)row * FEAT + lane * 8;
        const double* qp = Qd + (size_t)(lane * 8) * NBINS + jj;
        double p = 0.0;
#pragma unroll
        for (int u = 0; u < 8; u++) p = fma((double)xr[u], qp[u * NBINS], p);
#pragma unroll
        for (int off = 32; off > 0; off >>= 1) p += __shfl_xor(p, off, 64);
        const bool bit = p > cd[jj];
        if (lane == L) {
          if (bt == 0) b0[rg] = bit; else b1[rg] = bit;
        }
      }
    }
  // assemble per-row keys
#pragma unroll
  for (int rg = 0; rg < 4; rg++) {
    const unsigned mybits = (b0[rg] ? (1u << colbin) : 0u) |
                            (b1[rg] ? (1u << (16 + colbin)) : 0u);
    atomicOr(&keyParts[w * 16 + (lane >> 4) * 4 + rg], mybits);
  }
  __syncthreads();
  if (t < 64) {
    const int i = rowBase + t;
    unsigned key = keyParts[t];
    u64 combined = (u64)key;  // JAX int32 semantics: env<<32 vanished
    unsigned idx = (unsigned)((combined * 0x9E3779B97F4A7C15ull) >> 47) & TABMASK;
    for (;;) {
      u64 prev = atomicCAS(&keys_tab[idx], EMPTY, combined);
      if (prev == EMPTY || prev == combined) break;
      idx = (idx + 1) & TABMASK;
    }
    slot[i] = (int)idx;
    atomicAdd(&cnt[idx], 1u);
    nxt[i] = atomicExch(&head[idx], i);
  }
}

// ---------------- Kernel D: occurrence rank -> reward (unchanged)
__global__ __launch_bounds__(256) void count_kernel(
    const int* __restrict__ slot, const int* __restrict__ nxt,
    const int* __restrict__ head, const unsigned* __restrict__ cnt,
    float* __restrict__ out) {
  const int i = blockIdx.x * 256 + threadIdx.x;
  const int sl = slot[i];
  const unsigned c = cnt[sl];
  float r = 1.0f;
  if (c > 1u) {
    int j = head[sl];
    int occ = 1;
    while (j >= 0) {
      occ += (j < i) ? 1 : 0;
      j = nxt[j];
    }
    r = 1.0f / sqrtf((float)occ);
  }
  out[i] = r;
}

extern "C" void kernel_launch(void* const* d_in, const int* in_sizes, int n_in,
                              void* d_out, int out_size, void* d_ws, size_t ws_size,
                              hipStream_t stream) {
  const float4* xv = (const float4*)d_in[0];  // features f32 [64*1024][512]
  const float* feat = (const float*)d_in[0];
  const float* proj = (const float*)d_in[1];  // random_projection f32 [512][32]
  float* out = (float*)d_out;                 // [65536] f32
  char* ws = (char*)d_ws;

  u64* keys_tab = (u64*)(ws + OFF_KEYS);
  int* head = (int*)(ws + OFF_HEAD);
  unsigned* cnt = (unsigned*)(ws + OFF_CNT);
  u64* shad = (u64*)(ws + OFF_SHAD);
  unsigned* flag = (unsigned*)(ws + OFF_FLAG);
  double* Qd = (double*)(ws + OFF_QD);
  double* cd = (double*)(ws + OFF_CD);
  float* cf = (float*)(ws + OFF_CF);
  int* slot = (int*)(ws + OFF_SLOT);
  int* nxt = (int*)(ws + OFF_NEXT);
  u16* qfrag = (u16*)(ws + OFF_QFRAG);

  // init: keys_tab + head -> 0xFF (EMPTY / -1); cnt + shadows + flag -> 0
  (void)hipMemsetAsync(ws + OFF_KEYS, 0xFF, OFF_CNT - OFF_KEYS, stream);
  (void)hipMemsetAsync(ws + OFF_CNT, 0x00, OFF_QD - OFF_CNT, stream);

  colstats_kernel<<<NBLK_A, 256, 0, stream>>>(xv, proj, shad, flag, Qd, qfrag,
                                              cd, cf);
  project_kernel<<<N / 64, 256, 0, stream>>>(xv, feat, qfrag, cf, Qd, cd,
                                             keys_tab, head, cnt, slot, nxt);
  count_kernel<<<N / 256, 256, 0, stream>>>(slot, nxt, head, cnt, out);
}

// Round 4
// 269.449 us; speedup vs baseline: 1.6362x; 1.6362x over previous
//
#include <hip/hip_runtime.h>

using u16 = unsigned short;
using u64 = unsigned long long;
typedef short s16x8 __attribute__((ext_vector_type(8)));
typedef _Float16 f16x8 __attribute__((ext_vector_type(8)));
typedef unsigned short u16x4 __attribute__((ext_vector_type(4)));
typedef float f32x4 __attribute__((ext_vector_type(4)));

// Problem constants (fixed by reference)
constexpr int BATCH = 64, SEQ = 1024, FEAT = 512, NBINS = 32;
constexpr int N = BATCH * SEQ;              // 65536 samples
constexpr int TAB = 131072;                 // hash table slots (2N), pow2
constexpr unsigned TABMASK = TAB - 1;
constexpr u64 EMPTY = ~0ull;                // combined <= 2^32-1, safe sentinel
constexpr double FXSCALE = 67108864.0;      // 2^26 fixed-point for stat atomics
constexpr int NSHADOW = 64;                 // shadow accumulators (R7)

// NOTE (R4): JAX reference under default config runs int64 as int32;
// left_shift(env, 32) on int32 is 0 in XLA -> combined id is the 32-bit key
// ONLY (env dropped). Verified across rounds: absmax 0.0.
// NOTE (R3 lesson): NO __threadfence() in wide kernels — agent-scope fences
// on 8-XCD MI355X do L2 writeback/invalidate; 1024 blocks x fence = +235 us.
// Kernel-boundary ordering is free; keep finalize a separate dispatch.

// Workspace layout (bytes)
constexpr size_t OFF_KEYS = 0;              // u64[TAB]       1048576 (memset 0xFF)
constexpr size_t OFF_HEAD = 1048576;        // i32[TAB]       524288  (memset 0xFF -> -1)
constexpr size_t OFF_CNT = 1572864;         // u32[TAB]       524288  (memset 0x00)
constexpr size_t OFF_SHAD = 2097152;        // u64[64][1024]  524288  (memset 0x00)
constexpr size_t OFF_QD = 2621504;          // f64[16384]     131072  (Q = P/sigma, f64)
constexpr size_t OFF_CD = 2752576;          // f64[32]        256
constexpr size_t OFF_CF = 2818304;          // f32[32]        128
constexpr size_t OFF_SLOT = 2818432;        // i32[N]         262144
constexpr size_t OFF_NEXT = 3080576;        // i32[N]         262144
constexpr size_t OFF_QFRAG = 3342720;       // u16[16384]     32768 f16 B-frags
// qfrag layout: [ch(4)][ks(4)][bt(2)][lane(64)][j(8)] f16 bits
// element = B[k][bin], k = ch*128+ks*32+(lane>>4)*8+j, bin = bt*16+(lane&15)

__device__ inline u16 f2h(float f) {  // f32 -> f16 RNE (hardware cvt)
  _Float16 h = (_Float16)f;
  return __builtin_bit_cast(u16, h);
}

// ---------------- Kernel A: per-column sum / sumsq of f32 input.
// f64 regs; deterministic int fixed-point atomics into 64 shadow arrays.
__global__ __launch_bounds__(256, 4) void colstats_kernel(
    const float4* __restrict__ xv,  // f32 features, 8388608 float4s
    u64* __restrict__ shad) {
  const int t = threadIdx.x;
  const int L = blockIdx.x * 256 + t;  // 1024 blocks * 256 = 262144 threads
  double s0 = 0, s1 = 0, s2 = 0, s3 = 0, q0 = 0, q1 = 0, q2 = 0, q3 = 0;
  for (int mm = 0; mm < 32; mm += 8) {
    float4 v[8];
#pragma unroll
    for (int u = 0; u < 8; u++) v[u] = xv[L + (mm + u) * 262144];
#pragma unroll
    for (int u = 0; u < 8; u++) {
      double a = (double)v[u].x, b = (double)v[u].y;
      double c = (double)v[u].z, d = (double)v[u].w;
      s0 += a; s1 += b; s2 += c; s3 += d;
      q0 += a * a; q1 += b * b; q2 += c * c; q3 += d * d;
    }
  }
  __shared__ double red[256 * 8];  // 16 KB
  red[t * 8 + 0] = s0; red[t * 8 + 1] = s1; red[t * 8 + 2] = s2; red[t * 8 + 3] = s3;
  red[t * 8 + 4] = q0; red[t * 8 + 5] = q1; red[t * 8 + 6] = q2; red[t * 8 + 7] = q3;
  __syncthreads();
  if (t < 128) {
    // threads t and t+128 own the same 4 columns (262144 % 128 == 0)
    double v[8];
#pragma unroll
    for (int u = 0; u < 8; u++) v[u] = red[t * 8 + u] + red[(t + 128) * 8 + u];
    const int c0 = 4 * t;
    u64* sh = shad + (size_t)(blockIdx.x & (NSHADOW - 1)) * 1024;
#pragma unroll
    for (int u = 0; u < 4; u++) {
      long long a = (long long)llrint(v[u] * FXSCALE);
      long long b = (long long)llrint(v[4 + u] * FXSCALE);
      atomicAdd(&sh[c0 + u], (u64)a);
      atomicAdd(&sh[512 + c0 + u], (u64)b);
    }
  }
}

// ---------------- Kernel B: merge shadows (fixed order), finalize mean/inv-sigma
// (f64), emit Qd f64 (recheck), f16 B-fragments in MFMA lane order, cd, cf.
__global__ __launch_bounds__(512) void finalize_kernel(
    const float* __restrict__ P,  // f32 [512][32]
    const u64* __restrict__ shad,
    double* __restrict__ Qd, u16* __restrict__ qfrag,
    double* __restrict__ cd, float* __restrict__ cf) {
  __shared__ double meanArr[FEAT];
  __shared__ double invArr[FEAT];
  __shared__ double part[16][NBINS];
  const int t = threadIdx.x;  // t = feature index, 512 threads
  long long isum = 0, isumsq = 0;
  for (int sh = 0; sh < NSHADOW; sh++) {  // fixed order (int adds: exact anyway)
    isum += (long long)shad[sh * 1024 + t];
    isumsq += (long long)shad[sh * 1024 + 512 + t];
  }
  const double Nd = (double)N;
  const double tot = 1e-4 + Nd;
  double s = (double)isum * (1.0 / FXSCALE);
  double ss = (double)isumsq * (1.0 / FXSCALE);
  double bm = s / Nd;
  double bv = (ss - s * s / Nd) / (Nd - 1.0);  // unbiased var
  double mean = bm * Nd / tot;
  double M2 = 1e-4 + bv * Nd + bm * bm * 1e-4 * Nd / tot;
  double var = M2 / tot;
  double inv = 1.0 / sqrt(var + 1e-8);
  meanArr[t] = mean;
  invArr[t] = inv;
  // scatter f16 B-fragments (MFMA B lane order) + f64 Q for recheck
  const int ch = t >> 7, ks = (t >> 5) & 3, kg = (t >> 3) & 3, jlo = t & 7;
#pragma unroll
  for (int j = 0; j < NBINS; j++) {
    double qd = (double)P[t * NBINS + j] * inv;
    Qd[t * NBINS + j] = qd;
    const int lane = (j & 15) | (kg << 4);
    const int bt = j >> 4;
    qfrag[(size_t)((((ch * 4 + ks) * 2 + bt) * 64 + lane) * 8 + jlo)] =
        f2h((float)qd);
  }
  __syncthreads();
  // c reduction: thread t handles bin j=t&31, feature block g=t>>5 (32 feats)
  {
    const int j = t & 31, g = t >> 5;
    double p = 0.0;
    for (int f = g * 32; f < g * 32 + 32; f++) {
      double qd = (double)P[f * NBINS + j] * invArr[f];
      p += meanArr[f] * qd;
    }
    part[g][j] = p;
  }
  __syncthreads();
  if (t < NBINS) {
    double c = 0.0;
    for (int g = 0; g < 16; g++) c += part[g][t];  // fixed order -> deterministic
    cd[t] = c;
    cf[t] = (float)c;
  }
}

// ---------------- Kernel C: single-term f16 MFMA projection + hash insert.
// S = f16(x)*f16(q) accumulated in f32 MFMA. Margin error: sigma ~ 2.5e-4
// over K=512 (f16 u=2^-11), expected max over 2M bins ~ 1.4e-3. TAU = 4e-3
// (~16 sigma): any sign-ambiguous bin is re-decided by the wave-cooperative
// f64 dot. Verified R3: absmax 0.0.
constexpr float TAU = 4e-3f;
__global__ __launch_bounds__(256, 3) void project_kernel(
    const float4* __restrict__ xv, const float* __restrict__ feat,
    const u16* __restrict__ qfrag, const float* __restrict__ cf,
    const double* __restrict__ Qd, const double* __restrict__ cd,
    u64* __restrict__ keys_tab, int* __restrict__ head,
    unsigned* __restrict__ cnt, int* __restrict__ slot, int* __restrict__ nxt) {
  // A-frag LDS: [tile(w)*4+ks (16)][perm-lane (64)][j (8)] f16, 16 KB
  __shared__ __align__(16) u16 xh_lds[8192];
  __shared__ unsigned keyParts[64];
  const int t = threadIdx.x;
  const int rowBase = blockIdx.x * 64;
  const int lane = t & 63;
  const int w = t >> 6;  // wave id: owns rows rowBase + w*16 .. +16, all 32 bins
  if (t < 64) keyParts[t] = 0u;

  f32x4 acc0 = {0.f, 0.f, 0.f, 0.f};  // bins 0..15
  f32x4 acc1 = {0.f, 0.f, 0.f, 0.f};  // bins 16..31
  for (int ch = 0; ch < 4; ch++) {  // K chunks of 128
    __syncthreads();                // protects keyParts init / LDS reuse
    // B-fragments for this chunk -> 32 VGPRs (coalesced, L2-hot)
    s16x8 B[4][2];
#pragma unroll
    for (int ks = 0; ks < 4; ks++)
#pragma unroll
      for (int bt = 0; bt < 2; bt++)
        B[ks][bt] = *(const s16x8*)&qfrag[(size_t)((((ch * 4 + ks) * 2 + bt) * 64 + lane) * 8)];
    // stage X chunk: 64 rows x 32 float4 -> f16 in frag order (XOR swizzle)
#pragma unroll
    for (int kk = 0; kk < 8; kk++) {
      const int vi = t + kk * 256;
      const int r = vi >> 5, f4 = vi & 31;
      float4 v = xv[(size_t)(rowBase + r) * 128 + ch * 32 + f4];
      const int ks = f4 >> 3, kg = (f4 & 7) >> 1, j0 = (f4 & 1) * 4;
      const int lane_ = (r & 15) | (kg << 4);
      const int blk = ((r >> 4) * 4 + ks) * 64 + (lane_ ^ (((lane_ >> 4) & 3) << 1));
      u16x4 hv;
      hv[0] = f2h(v.x); hv[1] = f2h(v.y); hv[2] = f2h(v.z); hv[3] = f2h(v.w);
      *(u16x4*)&xh_lds[blk * 8 + j0] = hv;
    }
    __syncthreads();
    // MFMA: 4 k-steps x 2 bin-tiles
#pragma unroll
    for (int ks = 0; ks < 4; ks++) {
      const int rblk = (w * 4 + ks) * 64 + (lane ^ (((lane >> 4) & 3) << 1));
      f16x8 a = __builtin_bit_cast(f16x8, *(const s16x8*)&xh_lds[rblk * 8]);
      acc0 = __builtin_amdgcn_mfma_f32_16x16x32_f16(
          a, __builtin_bit_cast(f16x8, B[ks][0]), acc0, 0, 0, 0);
      acc1 = __builtin_amdgcn_mfma_f32_16x16x32_f16(
          a, __builtin_bit_cast(f16x8, B[ks][1]), acc1, 0, 0, 0);
    }
  }
  // C/D layout (verified): col = lane&15, row = (lane>>4)*4 + reg
  const int colbin = lane & 15;
  float m0[4], m1[4];
  bool b0[4], b1[4];
  const float c0v = cf[colbin], c1v = cf[16 + colbin];
#pragma unroll
  for (int rg = 0; rg < 4; rg++) {
    m0[rg] = acc0[rg] - c0v;
    m1[rg] = acc1[rg] - c1v;
    b0[rg] = m0[rg] > 0.0f;
    b1[rg] = m1[rg] > 0.0f;
  }
  // wave-cooperative f64 recheck of borderline bins (uniform control flow)
#pragma unroll
  for (int bt = 0; bt < 2; bt++)
#pragma unroll
    for (int rg = 0; rg < 4; rg++) {
      const float mv = (bt == 0) ? m0[rg] : m1[rg];
      u64 mask = __ballot(fabsf(mv) < TAU);
      while (mask) {
        const int L = (int)__builtin_ctzll(mask);
        mask &= mask - 1;
        const int jj = bt * 16 + (L & 15);
        const int row = rowBase + w * 16 + (L >> 4) * 4 + rg;
        const float* xr = feat + (size_t)row * FEAT + lane * 8;
        const double* qp = Qd + (size_t)(lane * 8) * NBINS + jj;
        double p = 0.0;
#pragma unroll
        for (int u = 0; u < 8; u++) p = fma((double)xr[u], qp[u * NBINS], p);
#pragma unroll
        for (int off = 32; off > 0; off >>= 1) p += __shfl_xor(p, off, 64);
        const bool bit = p > cd[jj];
        if (lane == L) {
          if (bt == 0) b0[rg] = bit; else b1[rg] = bit;
        }
      }
    }
  // assemble per-row keys
#pragma unroll
  for (int rg = 0; rg < 4; rg++) {
    const unsigned mybits = (b0[rg] ? (1u << colbin) : 0u) |
                            (b1[rg] ? (1u << (16 + colbin)) : 0u);
    atomicOr(&keyParts[w * 16 + (lane >> 4) * 4 + rg], mybits);
  }
  __syncthreads();
  if (t < 64) {
    const int i = rowBase + t;
    unsigned key = keyParts[t];
    u64 combined = (u64)key;  // JAX int32 semantics: env<<32 vanished
    unsigned idx = (unsigned)((combined * 0x9E3779B97F4A7C15ull) >> 47) & TABMASK;
    for (;;) {
      u64 prev = atomicCAS(&keys_tab[idx], EMPTY, combined);
      if (prev == EMPTY || prev == combined) break;
      idx = (idx + 1) & TABMASK;
    }
    slot[i] = (int)idx;
    atomicAdd(&cnt[idx], 1u);
    nxt[i] = atomicExch(&head[idx], i);
  }
}

// ---------------- Kernel D: occurrence rank -> reward (order-independent)
__global__ __launch_bounds__(256) void count_kernel(
    const int* __restrict__ slot, const int* __restrict__ nxt,
    const int* __restrict__ head, const unsigned* __restrict__ cnt,
    float* __restrict__ out) {
  const int i = blockIdx.x * 256 + threadIdx.x;
  const int sl = slot[i];
  const unsigned c = cnt[sl];
  float r = 1.0f;
  if (c > 1u) {
    int j = head[sl];
    int occ = 1;
    while (j >= 0) {
      occ += (j < i) ? 1 : 0;
      j = nxt[j];
    }
    r = 1.0f / sqrtf((float)occ);
  }
  out[i] = r;
}

extern "C" void kernel_launch(void* const* d_in, const int* in_sizes, int n_in,
                              void* d_out, int out_size, void* d_ws, size_t ws_size,
                              hipStream_t stream) {
  const float4* xv = (const float4*)d_in[0];  // features f32 [64*1024][512]
  const float* feat = (const float*)d_in[0];
  const float* proj = (const float*)d_in[1];  // random_projection f32 [512][32]
  float* out = (float*)d_out;                 // [65536] f32
  char* ws = (char*)d_ws;

  u64* keys_tab = (u64*)(ws + OFF_KEYS);
  int* head = (int*)(ws + OFF_HEAD);
  unsigned* cnt = (unsigned*)(ws + OFF_CNT);
  u64* shad = (u64*)(ws + OFF_SHAD);
  double* Qd = (double*)(ws + OFF_QD);
  double* cd = (double*)(ws + OFF_CD);
  float* cf = (float*)(ws + OFF_CF);
  int* slot = (int*)(ws + OFF_SLOT);
  int* nxt = (int*)(ws + OFF_NEXT);
  u16* qfrag = (u16*)(ws + OFF_QFRAG);

  // init: keys_tab + head -> 0xFF (EMPTY / -1); cnt + shadows -> 0
  (void)hipMemsetAsync(ws + OFF_KEYS, 0xFF, OFF_CNT - OFF_KEYS, stream);
  (void)hipMemsetAsync(ws + OFF_CNT, 0x00, OFF_QD - OFF_CNT, stream);

  colstats_kernel<<<1024, 256, 0, stream>>>(xv, shad);
  finalize_kernel<<<1, 512, 0, stream>>>(proj, shad, Qd, qfrag, cd, cf);
  project_kernel<<<N / 64, 256, 0, stream>>>(xv, feat, qfrag, cf, Qd, cd,
                                             keys_tab, head, cnt, slot, nxt);
  count_kernel<<<N / 256, 256, 0, stream>>>(slot, nxt, head, cnt, out);
}